// Round 2
// baseline (283.893 us; speedup 1.0000x reference)
//
#include <hip/hip_runtime.h>
#include <hip/hip_bf16.h>

#define NN 512      // nodes per graph
#define NE 8192     // edges per graph
#define NG 128      // graphs (B*G)
#define FH 128      // feature/hidden dim
#define APITCH 68   // A-chunk float pitch: 272 B row (16B-aligned), bank stride 4 -> 2-way (free)
#define XPITCH 136
#define BN_EPS 1e-5f

typedef __attribute__((ext_vector_type(8))) short s8v;            // 8 bf16 = 4 VGPRs
typedef __attribute__((ext_vector_type(4))) float f4v;            // MFMA C/D
typedef __attribute__((ext_vector_type(4))) unsigned short us4v;  // native ushort4
typedef __attribute__((ext_vector_type(4))) unsigned int u4v;

__device__ inline unsigned short f2bf(float x) {   // RNE fp32 -> bf16 bits
    unsigned u = __float_as_uint(x);
    unsigned r = (u + 0x7fffu + ((u >> 16) & 1u)) >> 16;
    return (unsigned short)r;
}
__device__ inline float bf2f(unsigned short h) { return __uint_as_float(((unsigned)h) << 16); }

// pack hi16(f1):hi16(f0) -> one u32 (exact bf16 for integer-valued floats < 256)
__device__ inline unsigned bfpack(int f1bits, int f0bits) {
    return __builtin_amdgcn_perm((unsigned)f1bits, (unsigned)f0bits, 0x07060302u);
}

// ---------------- K1: degrees + norms + 64-bucket (dstblk,srcchunk) packed edges;
//                 blocks >= NG: 2 pack W, 1 zeros partial/done ----------------
__global__ __launch_bounds__(1024) void k_build(const int* __restrict__ edges,
                                                float* __restrict__ rs_out,
                                                float* __restrict__ rs_in,
                                                int* __restrict__ bofs,
                                                unsigned short* __restrict__ epk,
                                                const float* __restrict__ W0,
                                                const float* __restrict__ W1,
                                                unsigned short* __restrict__ WP,
                                                float* __restrict__ partial,
                                                int* __restrict__ done) {
    int g = blockIdx.x;
    int tid = threadIdx.x;

    if (g >= NG) {
        int which = g - NG;
        if (which >= 2) {   // zero the head accumulators (workspace is poisoned)
            for (int i = tid; i < NG * FH; i += 1024) partial[i] = 0.f;
            if (tid < NG) done[tid] = 0;
            return;
        }
        const float* W = which ? W1 : W0;
        for (int task = tid; task < 2048; task += 1024) {
            int t = task >> 6;            // 0..31  (nt*4+kk)
            int lane = task & 63;
            int nt = t >> 2, kk = t & 3;
            int n = nt * 16 + (lane & 15);
            int k0 = kk * 32 + (lane >> 4) * 8;
            unsigned short* dh = WP + ((size_t)which * 2 + 0) * 16384 + ((size_t)t * 64 + lane) * 8;
            unsigned short* dl = WP + ((size_t)which * 2 + 1) * 16384 + ((size_t)t * 64 + lane) * 8;
#pragma unroll
            for (int j = 0; j < 8; j++) {
                float v = W[(size_t)(k0 + j) * FH + n];
                unsigned short h = f2bf(v);
                dh[j] = h;
                dl[j] = f2bf(v - bf2f(h));
            }
        }
        return;
    }

    const int* src = edges + (size_t)g * 2 * NE;
    const int* dst = src + NE;

    __shared__ int degO[NN], degI[NN];
    __shared__ int scanA[1024], scanB[1024];   // [bucket 64][replica 16] counts / scan ping-pong
    __shared__ int fill[1024];
    __shared__ unsigned short pk[NE];          // 16 KB packed edges

    for (int i = tid; i < NN; i += 1024) { degO[i] = 0; degI[i] = 0; }
    scanA[tid] = 0;
    __syncthreads();

    int rep = tid & 15;
    for (int u = tid; u < NE / 4; u += 1024) {
        int4 s = ((const int4*)src)[u];
        int4 d = ((const int4*)dst)[u];
        atomicAdd(&degO[s.x], 1); atomicAdd(&degO[s.y], 1);
        atomicAdd(&degO[s.z], 1); atomicAdd(&degO[s.w], 1);
        atomicAdd(&degI[d.x], 1); atomicAdd(&degI[d.y], 1);
        atomicAdd(&degI[d.z], 1); atomicAdd(&degI[d.w], 1);
        atomicAdd(&scanA[((((d.x >> 6) << 3) | (s.x >> 6)) << 4) + rep], 1);
        atomicAdd(&scanA[((((d.y >> 6) << 3) | (s.y >> 6)) << 4) + rep], 1);
        atomicAdd(&scanA[((((d.z >> 6) << 3) | (s.z >> 6)) << 4) + rep], 1);
        atomicAdd(&scanA[((((d.w >> 6) << 3) | (s.w >> 6)) << 4) + rep], 1);
    }
    __syncthreads();

    for (int i = tid; i < NN; i += 1024) {
        rs_out[g * NN + i] = rsqrtf((float)max(degO[i], 1));
        rs_in [g * NN + i] = rsqrtf((float)max(degI[i], 1));
    }

    // inclusive Hillis-Steele scan over the 1024 (bucket,replica) cells
    int* sA = scanA; int* sB = scanB;
    for (int off = 1; off < 1024; off <<= 1) {
        int v = sA[tid];
        if (tid >= off) v += sA[tid - off];
        sB[tid] = v;
        __syncthreads();
        int* t = sA; sA = sB; sB = t;
    }
    int excl = tid ? sA[tid - 1] : 0;
    fill[tid] = excl;
    if ((tid & 15) == 0) bofs[g * 65 + (tid >> 4)] = excl;   // bucket start = excl at cell b*16
    if (tid == 0) bofs[g * 65 + 64] = NE;
    __syncthreads();

    for (int u = tid; u < NE / 4; u += 1024) {
        int4 s = ((const int4*)src)[u];
        int4 d = ((const int4*)dst)[u];
        int c, p;
        c = ((((d.x >> 6) << 3) | (s.x >> 6)) << 4) + rep;
        p = atomicAdd(&fill[c], 1); pk[p] = (unsigned short)(((d.x & 63) << 6) | (s.x & 63));
        c = ((((d.y >> 6) << 3) | (s.y >> 6)) << 4) + rep;
        p = atomicAdd(&fill[c], 1); pk[p] = (unsigned short)(((d.y & 63) << 6) | (s.y & 63));
        c = ((((d.z >> 6) << 3) | (s.z >> 6)) << 4) + rep;
        p = atomicAdd(&fill[c], 1); pk[p] = (unsigned short)(((d.z & 63) << 6) | (s.z & 63));
        c = ((((d.w >> 6) << 3) | (s.w >> 6)) << 4) + rep;
        p = atomicAdd(&fill[c], 1); pk[p] = (unsigned short)(((d.w & 63) << 6) | (s.w & 63));
    }
    __syncthreads();
    // 8192 ushorts = 1024 int4, exactly one per thread
    ((int4*)(epk + (size_t)g * NE))[tid] = ((const int4*)pk)[tid];
}

// ---------------- K2: Y1f = pack_Bfrag((feats @ W0) * rs)  (hi/lo split, 3 MFMA) ----------------
__global__ __launch_bounds__(256) void k_gemm_f32(const float* __restrict__ X,
                                                  const unsigned short* __restrict__ WPh,
                                                  const unsigned short* __restrict__ WPl,
                                                  const float* __restrict__ rs,
                                                  unsigned short* __restrict__ Yf) {
    __shared__ unsigned short xh[64 * XPITCH];   // 17 KB
    __shared__ unsigned short xl[64 * XPITCH];   // 17 KB
    int tid = threadIdx.x;
    int sb = blockIdx.y;
    size_t r0 = (size_t)blockIdx.x * NN + (size_t)sb * 64;

    const float4* Xv = (const float4*)(X + r0 * FH);
#pragma unroll
    for (int i = 0; i < 8; i++) {
        int u = tid + i * 256;                 // 2048 float4 = 64x128
        int row = u >> 5, c4 = (u & 31) * 4;
        float4 v = Xv[u];
        int off = row * XPITCH + c4;
        unsigned short h0 = f2bf(v.x), h1 = f2bf(v.y), h2 = f2bf(v.z), h3 = f2bf(v.w);
        us4v hv, lv;
        hv.x = h0; hv.y = h1; hv.z = h2; hv.w = h3;
        lv.x = f2bf(v.x - bf2f(h0));
        lv.y = f2bf(v.y - bf2f(h1));
        lv.z = f2bf(v.z - bf2f(h2));
        lv.w = f2bf(v.w - bf2f(h3));
        *(us4v*)(xh + off) = hv;
        *(us4v*)(xl + off) = lv;
    }
    __syncthreads();

    int lane = tid & 63, w = tid >> 6;
    int quad = lane >> 4, m = lane & 15;
    int arow = w * 16 + m;

    f4v acc[8];
#pragma unroll
    for (int nt = 0; nt < 8; nt++) acc[nt] = (f4v){0.f, 0.f, 0.f, 0.f};

#pragma unroll
    for (int kk = 0; kk < 4; kk++) {
        s8v ah = *(const s8v*)&xh[arow * XPITCH + kk * 32 + quad * 8];
        s8v al = *(const s8v*)&xl[arow * XPITCH + kk * 32 + quad * 8];
#pragma unroll
        for (int nt = 0; nt < 8; nt++) {
            s8v bh = *(const s8v*)(WPh + ((size_t)(nt * 4 + kk) * 64 + lane) * 8);
            s8v bl = *(const s8v*)(WPl + ((size_t)(nt * 4 + kk) * 64 + lane) * 8);
            acc[nt] = __builtin_amdgcn_mfma_f32_16x16x32_bf16(ah, bh, acc[nt], 0, 0, 0);
            acc[nt] = __builtin_amdgcn_mfma_f32_16x16x32_bf16(al, bh, acc[nt], 0, 0, 0);
            acc[nt] = __builtin_amdgcn_mfma_f32_16x16x32_bf16(ah, bl, acc[nt], 0, 0, 0);
        }
    }

    int orow = w * 16 + quad * 4;
    float4 rsv = *(const float4*)(rs + r0 + orow);
    int tag = (w * 2 + (quad >> 1)) & 3;
    int kko = sb * 2 + (w >> 1);
    int j0  = (quad & 1) * 4;
    unsigned short* of = Yf + (size_t)blockIdx.x * (NN * FH);
#pragma unroll
    for (int nt = 0; nt < 8; nt++) {
        us4v v;
        v.x = f2bf(acc[nt][0] * rsv.x);
        v.y = f2bf(acc[nt][1] * rsv.y);
        v.z = f2bf(acc[nt][2] * rsv.z);
        v.w = f2bf(acc[nt][3] * rsv.w);
        *(us4v*)(of + (((size_t)kko * 8 + nt) * 64 + (m + 16 * tag)) * 8 + j0) = v;
    }
}

// ---------------- K3: FUSED dense-A MFMA aggregation (pipelined B/edge prefetch) + gemm2 -> Y2f ----------------
// T14: next pass's B-chunk (2x int4/thread) and edge value are loaded into regs right before
// the MFMA cluster, so L2 latency hides under compute; regs committed to LDS in the zero phase.
__global__ __launch_bounds__(512) void k_fused(const unsigned short* __restrict__ Y1f,
                                               const int* __restrict__ bofs,
                                               const unsigned short* __restrict__ epk,
                                               const float* __restrict__ rs_in,
                                               const float* __restrict__ rs_out,
                                               const float* __restrict__ bias,
                                               const unsigned short* __restrict__ WPh,
                                               const unsigned short* __restrict__ WPl,
                                               unsigned short* __restrict__ Y2f) {
    int g  = blockIdx.x;
    int sb = blockIdx.y;   // 0..7
    int tid = threadIdx.x;
    int lane = tid & 63, w8 = tid >> 6;    // 8 waves
    int quad = lane >> 4, m = lane & 15;
    int mt = w8 & 3, nh = w8 >> 2;
    int base = sb * 64;

    __shared__ float Af[64 * APITCH];             // 17408 B; hs aliases this after agg
    __shared__ unsigned short Bs[2 * 8 * 64 * 8]; // 16384 B B-chunk
    unsigned short* hs = (unsigned short*)Af;     // 64*XPITCH*2 = 17408 B exactly
    __shared__ float rsin_s[64];
    __shared__ int bo_s[9];

    const unsigned short* ep = epk + (size_t)g * NE;
    const int4* Yi4 = (const int4*)(Y1f + (size_t)g * (NN * FH));
    int4* Bi4 = (int4*)Bs;

    // prologue: B[0] loads issued immediately (land during setup)
    int4 rB0 = Yi4[tid];
    int4 rB1 = Yi4[tid + 512];

    if (tid < 64) rsin_s[tid] = rs_in[g * NN + base + tid];
    if (tid < 9) bo_s[tid] = bofs[g * 65 + sb * 8 + tid];
    __syncthreads();
    int evNext = -1;
    { int e0 = bo_s[0] + tid; if (e0 < bo_s[1]) evNext = (int)ep[e0]; }

    f4v acc[4];
#pragma unroll
    for (int j = 0; j < 4; j++) acc[j] = (f4v){0.f, 0.f, 0.f, 0.f};

    for (int p = 0; p < 8; p++) {
        if (p) __syncthreads();             // prior pass's Af/Bs reads done; drains prefetch loads (already landed)
        float4 z4 = {0.f, 0.f, 0.f, 0.f};
        for (int i = tid; i < 64 * APITCH / 4; i += 512) ((float4*)Af)[i] = z4;
        Bi4[tid] = rB0;                     // commit pass-p B-chunk
        Bi4[tid + 512] = rB1;
        __syncthreads();                    // zero + B visible
        if (evNext >= 0) atomicAdd(&Af[(evNext >> 6) * APITCH + (evNext & 63)], 1.0f);
        for (int e = bo_s[p] + tid + 512; e < bo_s[p + 1]; e += 512) {   // practically never taken
            int v = ep[e];
            atomicAdd(&Af[(v >> 6) * APITCH + (v & 63)], 1.0f);
        }
        __syncthreads();                    // A ready
        if (p < 7) {                        // prefetch pass p+1 (flies under MFMA)
            rB0 = Yi4[(p + 1) * 1024 + tid];
            rB1 = Yi4[(p + 1) * 1024 + tid + 512];
            int e1 = bo_s[p + 1] + tid;
            evNext = (e1 < bo_s[p + 2]) ? (int)ep[e1] : -1;
        }
#pragma unroll
        for (int kkl = 0; kkl < 2; kkl++) {
            s8v bf[4];
#pragma unroll
            for (int j = 0; j < 4; j++)
                bf[j] = *(const s8v*)&Bs[((kkl * 8 + nh * 4 + j) * 64 + lane) * 8];
            const int4* ap = (const int4*)&Af[(mt * 16 + m) * APITCH + kkl * 32 + quad * 8];
            int4 a0 = ap[0];
            int4 a1 = ap[1];
            union { u4v u; s8v s; } cv;
            cv.u.x = bfpack(a0.y, a0.x);
            cv.u.y = bfpack(a0.w, a0.z);
            cv.u.z = bfpack(a1.y, a1.x);
            cv.u.w = bfpack(a1.w, a1.z);
            s8v af = cv.s;
#pragma unroll
            for (int j = 0; j < 4; j++)
                acc[j] = __builtin_amdgcn_mfma_f32_16x16x32_bf16(af, bf[j], acc[j], 0, 0, 0);
        }
    }
    __syncthreads();   // agg done; Af reusable as hs

    // ---- conv1 epilogue: h = relu(rs_in*agg + b0) -> hs (natural [row][feat]) ----
#pragma unroll
    for (int j = 0; j < 4; j++) {
        int feat = (nh * 4 + j) * 16 + m;
        float bv = bias[feat];
#pragma unroll
        for (int i = 0; i < 4; i++) {
            int r = mt * 16 + quad * 4 + i;
            float hv = fmaxf(fmaf(rsin_s[r], acc[j][i], bv), 0.f);
            hs[r * XPITCH + feat] = f2bf(hv);
        }
    }
    __syncthreads();

    // ---- gemm2: Y2 = (h @ W1) * rs_out, packed B-fragment output ----
    f4v acc2[4];
#pragma unroll
    for (int j = 0; j < 4; j++) acc2[j] = (f4v){0.f, 0.f, 0.f, 0.f};

#pragma unroll
    for (int kk = 0; kk < 4; kk++) {
        s8v ah = *(const s8v*)&hs[(mt * 16 + m) * XPITCH + kk * 32 + quad * 8];
#pragma unroll
        for (int j = 0; j < 4; j++) {
            int nt = nh * 4 + j;
            s8v bh = *(const s8v*)(WPh + ((size_t)(nt * 4 + kk) * 64 + lane) * 8);
            s8v bl = *(const s8v*)(WPl + ((size_t)(nt * 4 + kk) * 64 + lane) * 8);
            acc2[j] = __builtin_amdgcn_mfma_f32_16x16x32_bf16(ah, bh, acc2[j], 0, 0, 0);
            acc2[j] = __builtin_amdgcn_mfma_f32_16x16x32_bf16(ah, bl, acc2[j], 0, 0, 0);
        }
    }

    int orow = mt * 16 + quad * 4;
    float4 rsv = *(const float4*)(rs_out + (size_t)g * NN + base + orow);
    int tag = (mt * 2 + (quad >> 1)) & 3;
    int kko = sb * 2 + (mt >> 1);
    int j0  = (quad & 1) * 4;
    unsigned short* of = Y2f + (size_t)g * (NN * FH);
#pragma unroll
    for (int j = 0; j < 4; j++) {
        int nt = nh * 4 + j;
        us4v v;
        v.x = f2bf(acc2[j][0] * rsv.x);
        v.y = f2bf(acc2[j][1] * rsv.y);
        v.z = f2bf(acc2[j][2] * rsv.z);
        v.w = f2bf(acc2[j][3] * rsv.w);
        *(us4v*)(of + (((size_t)kko * 8 + nt) * 64 + (m + 16 * tag)) * 8 + j0) = v;
    }
}

// ---------------- K4: dense-A MFMA aggregation (pipelined) + relu + node-sum + fused head ----------------
// partial accumulated via device atomics; the 8th (last) block per graph computes the
// head matvec + BN + relu (former K5), reading partial back with coherent atomic loads.
__global__ __launch_bounds__(512) void k_gather_mean(const unsigned short* __restrict__ Y2f,
                                                     const int* __restrict__ bofs,
                                                     const unsigned short* __restrict__ epk,
                                                     const float* __restrict__ rs_in,
                                                     const float* __restrict__ bias,
                                                     float* __restrict__ partial,
                                                     int* __restrict__ done,
                                                     const float* __restrict__ Wt,
                                                     const float* __restrict__ bt,
                                                     const float* __restrict__ gamma,
                                                     const float* __restrict__ beta,
                                                     const float* __restrict__ rmean,
                                                     const float* __restrict__ rvar,
                                                     float* __restrict__ out) {
    int g  = blockIdx.x;
    int sb = blockIdx.y;
    int tid = threadIdx.x;
    int lane = tid & 63, w8 = tid >> 6;
    int quad = lane >> 4, m = lane & 15;
    int mt = w8 & 3, nh = w8 >> 2;
    int base = sb * 64;

    __shared__ float Af[64 * APITCH];             // 17408 B; red aliases this after agg
    __shared__ unsigned short Bs[2 * 8 * 64 * 8]; // 16384 B
    float* red = (float*)Af;                      // [8][64][4] = 8192 B
    __shared__ float rsin_s[64];
    __shared__ int bo_s[9];
    __shared__ int lastFlag;

    const unsigned short* ep = epk + (size_t)g * NE;
    const int4* Yi4 = (const int4*)(Y2f + (size_t)g * (NN * FH));
    int4* Bi4 = (int4*)Bs;

    int4 rB0 = Yi4[tid];
    int4 rB1 = Yi4[tid + 512];

    if (tid < 64) rsin_s[tid] = rs_in[g * NN + base + tid];
    if (tid < 9) bo_s[tid] = bofs[g * 65 + sb * 8 + tid];
    __syncthreads();
    int evNext = -1;
    { int e0 = bo_s[0] + tid; if (e0 < bo_s[1]) evNext = (int)ep[e0]; }

    f4v acc[4];
#pragma unroll
    for (int j = 0; j < 4; j++) acc[j] = (f4v){0.f, 0.f, 0.f, 0.f};

    for (int p = 0; p < 8; p++) {
        if (p) __syncthreads();
        float4 z4 = {0.f, 0.f, 0.f, 0.f};
        for (int i = tid; i < 64 * APITCH / 4; i += 512) ((float4*)Af)[i] = z4;
        Bi4[tid] = rB0;
        Bi4[tid + 512] = rB1;
        __syncthreads();
        if (evNext >= 0) atomicAdd(&Af[(evNext >> 6) * APITCH + (evNext & 63)], 1.0f);
        for (int e = bo_s[p] + tid + 512; e < bo_s[p + 1]; e += 512) {
            int v = ep[e];
            atomicAdd(&Af[(v >> 6) * APITCH + (v & 63)], 1.0f);
        }
        __syncthreads();
        if (p < 7) {
            rB0 = Yi4[(p + 1) * 1024 + tid];
            rB1 = Yi4[(p + 1) * 1024 + tid + 512];
            int e1 = bo_s[p + 1] + tid;
            evNext = (e1 < bo_s[p + 2]) ? (int)ep[e1] : -1;
        }
#pragma unroll
        for (int kkl = 0; kkl < 2; kkl++) {
            s8v bf[4];
#pragma unroll
            for (int j = 0; j < 4; j++)
                bf[j] = *(const s8v*)&Bs[((kkl * 8 + nh * 4 + j) * 64 + lane) * 8];
            const int4* ap = (const int4*)&Af[(mt * 16 + m) * APITCH + kkl * 32 + quad * 8];
            int4 a0 = ap[0];
            int4 a1 = ap[1];
            union { u4v u; s8v s; } cv;
            cv.u.x = bfpack(a0.y, a0.x);
            cv.u.y = bfpack(a0.w, a0.z);
            cv.u.z = bfpack(a1.y, a1.x);
            cv.u.w = bfpack(a1.w, a1.z);
            s8v af = cv.s;
#pragma unroll
            for (int j = 0; j < 4; j++)
                acc[j] = __builtin_amdgcn_mfma_f32_16x16x32_bf16(af, bf[j], acc[j], 0, 0, 0);
        }
    }
    __syncthreads();   // agg done; Af reusable as red

    // ---- epilogue: relu(rs_in*agg + b1) summed over this lane's 4 rows, per nt ----
#pragma unroll
    for (int j = 0; j < 4; j++) {
        int feat = (nh * 4 + j) * 16 + m;
        float bv = bias[feat];
        float s = 0.f;
#pragma unroll
        for (int i = 0; i < 4; i++) {
            int r = mt * 16 + quad * 4 + i;
            s += fmaxf(fmaf(rsin_s[r], acc[j][i], bv), 0.f);
        }
        red[(w8 * 64 + lane) * 4 + j] = s;
    }
    __syncthreads();
    if (tid < FH) {
        int f = tid;
        int nt = f >> 4, mm = f & 15;
        int nhh = nt >> 2, jj = nt & 3;
        float t = 0.f;
#pragma unroll
        for (int mtt = 0; mtt < 4; mtt++)
#pragma unroll
            for (int q = 0; q < 4; q++)
                t += red[(((nhh * 4 + mtt) * 64) + q * 16 + mm) * 4 + jj];
        atomicAdd(&partial[(size_t)g * FH + f], t);
    }
    __threadfence();
    __syncthreads();               // all this block's partial adds retired (vmcnt drain)
    if (tid == 0) lastFlag = (atomicAdd(&done[g], 1) == 7) ? 1 : 0;
    __syncthreads();
    if (!lastFlag) return;

    // ---- fused head (former K5), last block of graph g only ----
    float* eh = (float*)Bs;        // Bs free now
    if (tid < FH) eh[tid] = atomicAdd(&partial[(size_t)g * FH + tid], 0.0f) * (1.0f / (float)NN);
    __syncthreads();
    if (tid < FH) {
        int j = tid;
        float a2 = bt[j];
#pragma unroll 8
        for (int k = 0; k < FH; k++) a2 += eh[k] * Wt[(size_t)k * FH + j];
        float z = gamma[j] * (a2 - rmean[j]) * rsqrtf(rvar[j] + BN_EPS) + beta[j];
        out[g * FH + j] = fmaxf(z, 0.f);
    }
}

extern "C" void kernel_launch(void* const* d_in, const int* in_sizes, int n_in,
                              void* d_out, int out_size, void* d_ws, size_t ws_size,
                              hipStream_t stream) {
    const float* feats = (const float*)d_in[0];
    const int*   edges = (const int*)d_in[1];
    const float* W0    = (const float*)d_in[2];
    const float* b0    = (const float*)d_in[3];
    const float* W1    = (const float*)d_in[4];
    const float* b1    = (const float*)d_in[5];
    const float* Wt    = (const float*)d_in[6];
    const float* bt    = (const float*)d_in[7];
    const float* gamma = (const float*)d_in[8];
    const float* beta  = (const float*)d_in[9];
    const float* rmean = (const float*)d_in[10];
    const float* rvar  = (const float*)d_in[11];
    float* out = (float*)d_out;

    // workspace layout
    char* w = (char*)d_ws;
    float* rs_out  = (float*)w;   w += sizeof(float) * NG * NN;
    float* rs_in   = (float*)w;   w += sizeof(float) * NG * NN;
    int*   bofs    = (int*)w;     w += sizeof(int) * NG * 65;              // 33280 B (16B multiple)
    unsigned short* epk = (unsigned short*)w; w += sizeof(unsigned short) * (size_t)NG * NE; // 2 MB
    unsigned short* WP  = (unsigned short*)w; w += sizeof(unsigned short) * 4 * 16384;       // 128 KB
    unsigned short* Y1  = (unsigned short*)w; w += sizeof(unsigned short) * (size_t)NG * NN * FH; // 16 MB
    unsigned short* Y2  = (unsigned short*)w; w += sizeof(unsigned short) * (size_t)NG * NN * FH; // 16 MB
    float* partial = (float*)w;   w += sizeof(float) * NG * FH;            // 64 KB
    int*   done    = (int*)w;     w += sizeof(int) * NG;

    unsigned short* WPh0 = WP;
    unsigned short* WPl0 = WP + 16384;
    unsigned short* WPh1 = WP + 32768;
    unsigned short* WPl1 = WP + 49152;

    // K1: norms + bucketed packed edges; extra blocks pack W0/W1 and zero partial/done
    k_build<<<NG + 3, 1024, 0, stream>>>(edges, rs_out, rs_in, bofs, epk, W0, W1, WP,
                                         partial, done);

    // K2: conv1 gemm (feats -> Y1, B-fragment packed)
    k_gemm_f32<<<dim3(NG, 8), 256, 0, stream>>>(feats, WPh0, WPl0, rs_out, Y1);

    // K3: fused dense-A MFMA aggregation (pipelined) + conv2 gemm (Y1 -> Y2, packed)
    k_fused<<<dim3(NG, 8), 512, 0, stream>>>(Y1, bofs, epk, rs_in, rs_out, b0, WPh1, WPl1, Y2);

    // K4: dense-A MFMA aggregation (pipelined, conv2) + node-mean + fused head
    k_gather_mean<<<dim3(NG, 8), 512, 0, stream>>>(Y2, bofs, epk, rs_in, b1, partial, done,
                                                   Wt, bt, gamma, beta, rmean, rvar, out);

    (void)in_sizes; (void)n_in; (void)out_size; (void)ws_size;
}

// Round 3
// 173.989 us; speedup vs baseline: 1.6317x; 1.6317x over previous
//
#include <hip/hip_runtime.h>
#include <hip/hip_bf16.h>

#define NN 512      // nodes per graph
#define NE 8192     // edges per graph
#define NG 128      // graphs (B*G)
#define FH 128      // feature/hidden dim
#define APITCH 68   // A-chunk float pitch: 272 B row (16B-aligned), bank stride 4 -> 2-way (free)
#define XPITCH 136
#define BN_EPS 1e-5f

typedef __attribute__((ext_vector_type(8))) short s8v;            // 8 bf16 = 4 VGPRs
typedef __attribute__((ext_vector_type(4))) float f4v;            // MFMA C/D
typedef __attribute__((ext_vector_type(4))) unsigned short us4v;  // native ushort4
typedef __attribute__((ext_vector_type(4))) unsigned int u4v;

__device__ inline unsigned short f2bf(float x) {   // RNE fp32 -> bf16 bits
    unsigned u = __float_as_uint(x);
    unsigned r = (u + 0x7fffu + ((u >> 16) & 1u)) >> 16;
    return (unsigned short)r;
}
__device__ inline float bf2f(unsigned short h) { return __uint_as_float(((unsigned)h) << 16); }

// pack hi16(f1):hi16(f0) -> one u32 (exact bf16 for integer-valued floats < 256)
__device__ inline unsigned bfpack(int f1bits, int f0bits) {
    return __builtin_amdgcn_perm((unsigned)f1bits, (unsigned)f0bits, 0x07060302u);
}

// ---------------- K1: degrees + norms + 64-bucket (dstblk,srcchunk) packed edges; blocks >= NG pack W ----------------
__global__ __launch_bounds__(1024) void k_build(const int* __restrict__ edges,
                                                float* __restrict__ rs_out,
                                                float* __restrict__ rs_in,
                                                int* __restrict__ bofs,
                                                unsigned short* __restrict__ epk,
                                                const float* __restrict__ W0,
                                                const float* __restrict__ W1,
                                                unsigned short* __restrict__ WP) {
    int g = blockIdx.x;
    int tid = threadIdx.x;

    if (g >= NG) {
        int which = g - NG;
        const float* W = which ? W1 : W0;
        for (int task = tid; task < 2048; task += 1024) {
            int t = task >> 6;            // 0..31  (nt*4+kk)
            int lane = task & 63;
            int nt = t >> 2, kk = t & 3;
            int n = nt * 16 + (lane & 15);
            int k0 = kk * 32 + (lane >> 4) * 8;
            unsigned short* dh = WP + ((size_t)which * 2 + 0) * 16384 + ((size_t)t * 64 + lane) * 8;
            unsigned short* dl = WP + ((size_t)which * 2 + 1) * 16384 + ((size_t)t * 64 + lane) * 8;
#pragma unroll
            for (int j = 0; j < 8; j++) {
                float v = W[(size_t)(k0 + j) * FH + n];
                unsigned short h = f2bf(v);
                dh[j] = h;
                dl[j] = f2bf(v - bf2f(h));
            }
        }
        return;
    }

    const int* src = edges + (size_t)g * 2 * NE;
    const int* dst = src + NE;

    __shared__ int degO[NN], degI[NN];
    __shared__ int scanA[1024], scanB[1024];   // [bucket 64][replica 16] counts / scan ping-pong
    __shared__ int fill[1024];
    __shared__ unsigned short pk[NE];          // 16 KB packed edges

    for (int i = tid; i < NN; i += 1024) { degO[i] = 0; degI[i] = 0; }
    scanA[tid] = 0;
    __syncthreads();

    int rep = tid & 15;
    for (int u = tid; u < NE / 4; u += 1024) {
        int4 s = ((const int4*)src)[u];
        int4 d = ((const int4*)dst)[u];
        atomicAdd(&degO[s.x], 1); atomicAdd(&degO[s.y], 1);
        atomicAdd(&degO[s.z], 1); atomicAdd(&degO[s.w], 1);
        atomicAdd(&degI[d.x], 1); atomicAdd(&degI[d.y], 1);
        atomicAdd(&degI[d.z], 1); atomicAdd(&degI[d.w], 1);
        atomicAdd(&scanA[((((d.x >> 6) << 3) | (s.x >> 6)) << 4) + rep], 1);
        atomicAdd(&scanA[((((d.y >> 6) << 3) | (s.y >> 6)) << 4) + rep], 1);
        atomicAdd(&scanA[((((d.z >> 6) << 3) | (s.z >> 6)) << 4) + rep], 1);
        atomicAdd(&scanA[((((d.w >> 6) << 3) | (s.w >> 6)) << 4) + rep], 1);
    }
    __syncthreads();

    for (int i = tid; i < NN; i += 1024) {
        rs_out[g * NN + i] = rsqrtf((float)max(degO[i], 1));
        rs_in [g * NN + i] = rsqrtf((float)max(degI[i], 1));
    }

    // inclusive Hillis-Steele scan over the 1024 (bucket,replica) cells
    int* sA = scanA; int* sB = scanB;
    for (int off = 1; off < 1024; off <<= 1) {
        int v = sA[tid];
        if (tid >= off) v += sA[tid - off];
        sB[tid] = v;
        __syncthreads();
        int* t = sA; sA = sB; sB = t;
    }
    int excl = tid ? sA[tid - 1] : 0;
    fill[tid] = excl;
    if ((tid & 15) == 0) bofs[g * 65 + (tid >> 4)] = excl;   // bucket start = excl at cell b*16
    if (tid == 0) bofs[g * 65 + 64] = NE;
    __syncthreads();

    for (int u = tid; u < NE / 4; u += 1024) {
        int4 s = ((const int4*)src)[u];
        int4 d = ((const int4*)dst)[u];
        int c, p;
        c = ((((d.x >> 6) << 3) | (s.x >> 6)) << 4) + rep;
        p = atomicAdd(&fill[c], 1); pk[p] = (unsigned short)(((d.x & 63) << 6) | (s.x & 63));
        c = ((((d.y >> 6) << 3) | (s.y >> 6)) << 4) + rep;
        p = atomicAdd(&fill[c], 1); pk[p] = (unsigned short)(((d.y & 63) << 6) | (s.y & 63));
        c = ((((d.z >> 6) << 3) | (s.z >> 6)) << 4) + rep;
        p = atomicAdd(&fill[c], 1); pk[p] = (unsigned short)(((d.z & 63) << 6) | (s.z & 63));
        c = ((((d.w >> 6) << 3) | (s.w >> 6)) << 4) + rep;
        p = atomicAdd(&fill[c], 1); pk[p] = (unsigned short)(((d.w & 63) << 6) | (s.w & 63));
    }
    __syncthreads();
    // 8192 ushorts = 1024 int4, exactly one per thread
    ((int4*)(epk + (size_t)g * NE))[tid] = ((const int4*)pk)[tid];
}

// ---------------- K2: Y1f = pack_Bfrag((feats @ W0) * rs)  (hi/lo split, 3 MFMA) ----------------
__global__ __launch_bounds__(256) void k_gemm_f32(const float* __restrict__ X,
                                                  const unsigned short* __restrict__ WPh,
                                                  const unsigned short* __restrict__ WPl,
                                                  const float* __restrict__ rs,
                                                  unsigned short* __restrict__ Yf) {
    __shared__ unsigned short xh[64 * XPITCH];   // 17 KB
    __shared__ unsigned short xl[64 * XPITCH];   // 17 KB
    int tid = threadIdx.x;
    int sb = blockIdx.y;
    size_t r0 = (size_t)blockIdx.x * NN + (size_t)sb * 64;

    const float4* Xv = (const float4*)(X + r0 * FH);
#pragma unroll
    for (int i = 0; i < 8; i++) {
        int u = tid + i * 256;                 // 2048 float4 = 64x128
        int row = u >> 5, c4 = (u & 31) * 4;
        float4 v = Xv[u];
        int off = row * XPITCH + c4;
        unsigned short h0 = f2bf(v.x), h1 = f2bf(v.y), h2 = f2bf(v.z), h3 = f2bf(v.w);
        us4v hv, lv;
        hv.x = h0; hv.y = h1; hv.z = h2; hv.w = h3;
        lv.x = f2bf(v.x - bf2f(h0));
        lv.y = f2bf(v.y - bf2f(h1));
        lv.z = f2bf(v.z - bf2f(h2));
        lv.w = f2bf(v.w - bf2f(h3));
        *(us4v*)(xh + off) = hv;
        *(us4v*)(xl + off) = lv;
    }
    __syncthreads();

    int lane = tid & 63, w = tid >> 6;
    int quad = lane >> 4, m = lane & 15;
    int arow = w * 16 + m;

    f4v acc[8];
#pragma unroll
    for (int nt = 0; nt < 8; nt++) acc[nt] = (f4v){0.f, 0.f, 0.f, 0.f};

#pragma unroll
    for (int kk = 0; kk < 4; kk++) {
        s8v ah = *(const s8v*)&xh[arow * XPITCH + kk * 32 + quad * 8];
        s8v al = *(const s8v*)&xl[arow * XPITCH + kk * 32 + quad * 8];
#pragma unroll
        for (int nt = 0; nt < 8; nt++) {
            s8v bh = *(const s8v*)(WPh + ((size_t)(nt * 4 + kk) * 64 + lane) * 8);
            s8v bl = *(const s8v*)(WPl + ((size_t)(nt * 4 + kk) * 64 + lane) * 8);
            acc[nt] = __builtin_amdgcn_mfma_f32_16x16x32_bf16(ah, bh, acc[nt], 0, 0, 0);
            acc[nt] = __builtin_amdgcn_mfma_f32_16x16x32_bf16(al, bh, acc[nt], 0, 0, 0);
            acc[nt] = __builtin_amdgcn_mfma_f32_16x16x32_bf16(ah, bl, acc[nt], 0, 0, 0);
        }
    }

    int orow = w * 16 + quad * 4;
    float4 rsv = *(const float4*)(rs + r0 + orow);
    int tag = (w * 2 + (quad >> 1)) & 3;
    int kko = sb * 2 + (w >> 1);
    int j0  = (quad & 1) * 4;
    unsigned short* of = Yf + (size_t)blockIdx.x * (NN * FH);
#pragma unroll
    for (int nt = 0; nt < 8; nt++) {
        us4v v;
        v.x = f2bf(acc[nt][0] * rsv.x);
        v.y = f2bf(acc[nt][1] * rsv.y);
        v.z = f2bf(acc[nt][2] * rsv.z);
        v.w = f2bf(acc[nt][3] * rsv.w);
        *(us4v*)(of + (((size_t)kko * 8 + nt) * 64 + (m + 16 * tag)) * 8 + j0) = v;
    }
}

// ---------------- K3: FUSED dense-A MFMA aggregation (pipelined B/edge prefetch) + gemm2 -> Y2f ----------------
// T14: next pass's B-chunk (2x int4/thread) and edge value are loaded into regs right before
// the MFMA cluster, so L2 latency hides under compute; regs committed to LDS in the zero phase.
__global__ __launch_bounds__(512) void k_fused(const unsigned short* __restrict__ Y1f,
                                               const int* __restrict__ bofs,
                                               const unsigned short* __restrict__ epk,
                                               const float* __restrict__ rs_in,
                                               const float* __restrict__ rs_out,
                                               const float* __restrict__ bias,
                                               const unsigned short* __restrict__ WPh,
                                               const unsigned short* __restrict__ WPl,
                                               unsigned short* __restrict__ Y2f) {
    int g  = blockIdx.x;
    int sb = blockIdx.y;   // 0..7
    int tid = threadIdx.x;
    int lane = tid & 63, w8 = tid >> 6;    // 8 waves
    int quad = lane >> 4, m = lane & 15;
    int mt = w8 & 3, nh = w8 >> 2;
    int base = sb * 64;

    __shared__ float Af[64 * APITCH];             // 17408 B; hs aliases this after agg
    __shared__ unsigned short Bs[2 * 8 * 64 * 8]; // 16384 B B-chunk
    unsigned short* hs = (unsigned short*)Af;     // 64*XPITCH*2 = 17408 B exactly
    __shared__ float rsin_s[64];
    __shared__ int bo_s[9];

    const unsigned short* ep = epk + (size_t)g * NE;
    const int4* Yi4 = (const int4*)(Y1f + (size_t)g * (NN * FH));
    int4* Bi4 = (int4*)Bs;

    // prologue: B[0] loads issued immediately (land during setup)
    int4 rB0 = Yi4[tid];
    int4 rB1 = Yi4[tid + 512];

    if (tid < 64) rsin_s[tid] = rs_in[g * NN + base + tid];
    if (tid < 9) bo_s[tid] = bofs[g * 65 + sb * 8 + tid];
    __syncthreads();
    int evNext = -1;
    { int e0 = bo_s[0] + tid; if (e0 < bo_s[1]) evNext = (int)ep[e0]; }

    f4v acc[4];
#pragma unroll
    for (int j = 0; j < 4; j++) acc[j] = (f4v){0.f, 0.f, 0.f, 0.f};

    for (int p = 0; p < 8; p++) {
        if (p) __syncthreads();             // prior pass's Af/Bs reads done; drains prefetch loads (already landed)
        float4 z4 = {0.f, 0.f, 0.f, 0.f};
        for (int i = tid; i < 64 * APITCH / 4; i += 512) ((float4*)Af)[i] = z4;
        Bi4[tid] = rB0;                     // commit pass-p B-chunk
        Bi4[tid + 512] = rB1;
        __syncthreads();                    // zero + B visible
        if (evNext >= 0) atomicAdd(&Af[(evNext >> 6) * APITCH + (evNext & 63)], 1.0f);
        for (int e = bo_s[p] + tid + 512; e < bo_s[p + 1]; e += 512) {   // practically never taken
            int v = ep[e];
            atomicAdd(&Af[(v >> 6) * APITCH + (v & 63)], 1.0f);
        }
        __syncthreads();                    // A ready
        if (p < 7) {                        // prefetch pass p+1 (flies under MFMA)
            rB0 = Yi4[(p + 1) * 1024 + tid];
            rB1 = Yi4[(p + 1) * 1024 + tid + 512];
            int e1 = bo_s[p + 1] + tid;
            evNext = (e1 < bo_s[p + 2]) ? (int)ep[e1] : -1;
        }
#pragma unroll
        for (int kkl = 0; kkl < 2; kkl++) {
            s8v bf[4];
#pragma unroll
            for (int j = 0; j < 4; j++)
                bf[j] = *(const s8v*)&Bs[((kkl * 8 + nh * 4 + j) * 64 + lane) * 8];
            const int4* ap = (const int4*)&Af[(mt * 16 + m) * APITCH + kkl * 32 + quad * 8];
            int4 a0 = ap[0];
            int4 a1 = ap[1];
            union { u4v u; s8v s; } cv;
            cv.u.x = bfpack(a0.y, a0.x);
            cv.u.y = bfpack(a0.w, a0.z);
            cv.u.z = bfpack(a1.y, a1.x);
            cv.u.w = bfpack(a1.w, a1.z);
            s8v af = cv.s;
#pragma unroll
            for (int j = 0; j < 4; j++)
                acc[j] = __builtin_amdgcn_mfma_f32_16x16x32_bf16(af, bf[j], acc[j], 0, 0, 0);
        }
    }
    __syncthreads();   // agg done; Af reusable as hs

    // ---- conv1 epilogue: h = relu(rs_in*agg + b0) -> hs (natural [row][feat]) ----
#pragma unroll
    for (int j = 0; j < 4; j++) {
        int feat = (nh * 4 + j) * 16 + m;
        float bv = bias[feat];
#pragma unroll
        for (int i = 0; i < 4; i++) {
            int r = mt * 16 + quad * 4 + i;
            float hv = fmaxf(fmaf(rsin_s[r], acc[j][i], bv), 0.f);
            hs[r * XPITCH + feat] = f2bf(hv);
        }
    }
    __syncthreads();

    // ---- gemm2: Y2 = (h @ W1) * rs_out, packed B-fragment output ----
    f4v acc2[4];
#pragma unroll
    for (int j = 0; j < 4; j++) acc2[j] = (f4v){0.f, 0.f, 0.f, 0.f};

#pragma unroll
    for (int kk = 0; kk < 4; kk++) {
        s8v ah = *(const s8v*)&hs[(mt * 16 + m) * XPITCH + kk * 32 + quad * 8];
#pragma unroll
        for (int j = 0; j < 4; j++) {
            int nt = nh * 4 + j;
            s8v bh = *(const s8v*)(WPh + ((size_t)(nt * 4 + kk) * 64 + lane) * 8);
            s8v bl = *(const s8v*)(WPl + ((size_t)(nt * 4 + kk) * 64 + lane) * 8);
            acc2[j] = __builtin_amdgcn_mfma_f32_16x16x32_bf16(ah, bh, acc2[j], 0, 0, 0);
            acc2[j] = __builtin_amdgcn_mfma_f32_16x16x32_bf16(ah, bl, acc2[j], 0, 0, 0);
        }
    }

    int orow = mt * 16 + quad * 4;
    float4 rsv = *(const float4*)(rs_out + (size_t)g * NN + base + orow);
    int tag = (mt * 2 + (quad >> 1)) & 3;
    int kko = sb * 2 + (mt >> 1);
    int j0  = (quad & 1) * 4;
    unsigned short* of = Y2f + (size_t)g * (NN * FH);
#pragma unroll
    for (int j = 0; j < 4; j++) {
        int nt = nh * 4 + j;
        us4v v;
        v.x = f2bf(acc2[j][0] * rsv.x);
        v.y = f2bf(acc2[j][1] * rsv.y);
        v.z = f2bf(acc2[j][2] * rsv.z);
        v.w = f2bf(acc2[j][3] * rsv.w);
        *(us4v*)(of + (((size_t)kko * 8 + nt) * 64 + (m + 16 * tag)) * 8 + j0) = v;
    }
}

// ---------------- K4: dense-A MFMA aggregation (pipelined) + relu + node-sum -> partial ----------------
__global__ __launch_bounds__(512) void k_gather_mean(const unsigned short* __restrict__ Y2f,
                                                     const int* __restrict__ bofs,
                                                     const unsigned short* __restrict__ epk,
                                                     const float* __restrict__ rs_in,
                                                     const float* __restrict__ bias,
                                                     float* __restrict__ partial) {
    int g  = blockIdx.x;
    int sb = blockIdx.y;
    int tid = threadIdx.x;
    int lane = tid & 63, w8 = tid >> 6;
    int quad = lane >> 4, m = lane & 15;
    int mt = w8 & 3, nh = w8 >> 2;
    int base = sb * 64;

    __shared__ float Af[64 * APITCH];             // 17408 B; red aliases this after agg
    __shared__ unsigned short Bs[2 * 8 * 64 * 8]; // 16384 B
    float* red = (float*)Af;                      // [8][64][4] = 8192 B
    __shared__ float rsin_s[64];
    __shared__ int bo_s[9];

    const unsigned short* ep = epk + (size_t)g * NE;
    const int4* Yi4 = (const int4*)(Y2f + (size_t)g * (NN * FH));
    int4* Bi4 = (int4*)Bs;

    int4 rB0 = Yi4[tid];
    int4 rB1 = Yi4[tid + 512];

    if (tid < 64) rsin_s[tid] = rs_in[g * NN + base + tid];
    if (tid < 9) bo_s[tid] = bofs[g * 65 + sb * 8 + tid];
    __syncthreads();
    int evNext = -1;
    { int e0 = bo_s[0] + tid; if (e0 < bo_s[1]) evNext = (int)ep[e0]; }

    f4v acc[4];
#pragma unroll
    for (int j = 0; j < 4; j++) acc[j] = (f4v){0.f, 0.f, 0.f, 0.f};

    for (int p = 0; p < 8; p++) {
        if (p) __syncthreads();
        float4 z4 = {0.f, 0.f, 0.f, 0.f};
        for (int i = tid; i < 64 * APITCH / 4; i += 512) ((float4*)Af)[i] = z4;
        Bi4[tid] = rB0;
        Bi4[tid + 512] = rB1;
        __syncthreads();
        if (evNext >= 0) atomicAdd(&Af[(evNext >> 6) * APITCH + (evNext & 63)], 1.0f);
        for (int e = bo_s[p] + tid + 512; e < bo_s[p + 1]; e += 512) {
            int v = ep[e];
            atomicAdd(&Af[(v >> 6) * APITCH + (v & 63)], 1.0f);
        }
        __syncthreads();
        if (p < 7) {
            rB0 = Yi4[(p + 1) * 1024 + tid];
            rB1 = Yi4[(p + 1) * 1024 + tid + 512];
            int e1 = bo_s[p + 1] + tid;
            evNext = (e1 < bo_s[p + 2]) ? (int)ep[e1] : -1;
        }
#pragma unroll
        for (int kkl = 0; kkl < 2; kkl++) {
            s8v bf[4];
#pragma unroll
            for (int j = 0; j < 4; j++)
                bf[j] = *(const s8v*)&Bs[((kkl * 8 + nh * 4 + j) * 64 + lane) * 8];
            const int4* ap = (const int4*)&Af[(mt * 16 + m) * APITCH + kkl * 32 + quad * 8];
            int4 a0 = ap[0];
            int4 a1 = ap[1];
            union { u4v u; s8v s; } cv;
            cv.u.x = bfpack(a0.y, a0.x);
            cv.u.y = bfpack(a0.w, a0.z);
            cv.u.z = bfpack(a1.y, a1.x);
            cv.u.w = bfpack(a1.w, a1.z);
            s8v af = cv.s;
#pragma unroll
            for (int j = 0; j < 4; j++)
                acc[j] = __builtin_amdgcn_mfma_f32_16x16x32_bf16(af, bf[j], acc[j], 0, 0, 0);
        }
    }
    __syncthreads();   // agg done; Af reusable as red

    // ---- epilogue: relu(rs_in*agg + b1) summed over this lane's 4 rows, per nt ----
#pragma unroll
    for (int j = 0; j < 4; j++) {
        int feat = (nh * 4 + j) * 16 + m;
        float bv = bias[feat];
        float s = 0.f;
#pragma unroll
        for (int i = 0; i < 4; i++) {
            int r = mt * 16 + quad * 4 + i;
            s += fmaxf(fmaf(rsin_s[r], acc[j][i], bv), 0.f);
        }
        red[(w8 * 64 + lane) * 4 + j] = s;
    }
    __syncthreads();
    if (tid < FH) {
        int f = tid;
        int nt = f >> 4, mm = f & 15;
        int nhh = nt >> 2, jj = nt & 3;
        float t = 0.f;
#pragma unroll
        for (int mtt = 0; mtt < 4; mtt++)
#pragma unroll
            for (int q = 0; q < 4; q++)
                t += red[(((nhh * 4 + mtt) * 64) + q * 16 + mm) * 4 + jj];
        partial[((size_t)g * 8 + sb) * FH + f] = t;
    }
}

// ---------------- K5: z = (sum partials)/512 @ Wt + bt; BN eval; relu ----------------
__global__ __launch_bounds__(128) void k_head(const float* __restrict__ partial,
                                              const float* __restrict__ Wt,
                                              const float* __restrict__ bt,
                                              const float* __restrict__ gamma,
                                              const float* __restrict__ beta,
                                              const float* __restrict__ rmean,
                                              const float* __restrict__ rvar,
                                              float* __restrict__ out) {
    int g = blockIdx.x;
    int j = threadIdx.x;
    __shared__ float e[FH];
    float acc8 = 0.f;
#pragma unroll
    for (int q = 0; q < 8; q++) acc8 += partial[((size_t)g * 8 + q) * FH + j];
    e[j] = acc8 * (1.0f / (float)NN);
    __syncthreads();
    float acc = bt[j];
#pragma unroll 8
    for (int k = 0; k < FH; k++) acc += e[k] * Wt[(size_t)k * FH + j];
    float z = gamma[j] * (acc - rmean[j]) * rsqrtf(rvar[j] + BN_EPS) + beta[j];
    out[g * FH + j] = fmaxf(z, 0.f);
}

extern "C" void kernel_launch(void* const* d_in, const int* in_sizes, int n_in,
                              void* d_out, int out_size, void* d_ws, size_t ws_size,
                              hipStream_t stream) {
    const float* feats = (const float*)d_in[0];
    const int*   edges = (const int*)d_in[1];
    const float* W0    = (const float*)d_in[2];
    const float* b0    = (const float*)d_in[3];
    const float* W1    = (const float*)d_in[4];
    const float* b1    = (const float*)d_in[5];
    const float* Wt    = (const float*)d_in[6];
    const float* bt    = (const float*)d_in[7];
    const float* gamma = (const float*)d_in[8];
    const float* beta  = (const float*)d_in[9];
    const float* rmean = (const float*)d_in[10];
    const float* rvar  = (const float*)d_in[11];
    float* out = (float*)d_out;

    // workspace layout
    char* w = (char*)d_ws;
    float* rs_out  = (float*)w;   w += sizeof(float) * NG * NN;
    float* rs_in   = (float*)w;   w += sizeof(float) * NG * NN;
    int*   bofs    = (int*)w;     w += sizeof(int) * NG * 65;              // 33280 B (16B multiple)
    unsigned short* epk = (unsigned short*)w; w += sizeof(unsigned short) * (size_t)NG * NE; // 2 MB
    unsigned short* WP  = (unsigned short*)w; w += sizeof(unsigned short) * 4 * 16384;       // 128 KB
    unsigned short* Y1  = (unsigned short*)w; w += sizeof(unsigned short) * (size_t)NG * NN * FH; // 16 MB
    unsigned short* Y2  = (unsigned short*)w; w += sizeof(unsigned short) * (size_t)NG * NN * FH; // 16 MB
    float* partial = (float*)w;   w += sizeof(float) * NG * 8 * FH;

    unsigned short* WPh0 = WP;
    unsigned short* WPl0 = WP + 16384;
    unsigned short* WPh1 = WP + 32768;
    unsigned short* WPl1 = WP + 49152;

    // K1: norms + bucketed packed edges; 2 extra blocks pack W0/W1
    k_build<<<NG + 2, 1024, 0, stream>>>(edges, rs_out, rs_in, bofs, epk, W0, W1, WP);

    // K2: conv1 gemm (feats -> Y1, B-fragment packed)
    k_gemm_f32<<<dim3(NG, 8), 256, 0, stream>>>(feats, WPh0, WPl0, rs_out, Y1);

    // K3: fused dense-A MFMA aggregation (pipelined) + conv2 gemm (Y1 -> Y2, packed)
    k_fused<<<dim3(NG, 8), 512, 0, stream>>>(Y1, bofs, epk, rs_in, rs_out, b0, WPh1, WPl1, Y2);

    // K4: dense-A MFMA aggregation (pipelined, conv2) + node-mean -> partial
    k_gather_mean<<<dim3(NG, 8), 512, 0, stream>>>(Y2, bofs, epk, rs_in, b1, partial);

    // K5: head
    k_head<<<NG, 128, 0, stream>>>(partial, Wt, bt, gamma, beta, rmean, rvar, out);

    (void)in_sizes; (void)n_in; (void)out_size; (void)ws_size;
}

// Round 4
// 173.628 us; speedup vs baseline: 1.6351x; 1.0021x over previous
//
#include <hip/hip_runtime.h>
#include <hip/hip_bf16.h>

#define NN 512      // nodes per graph
#define NE 8192     // edges per graph
#define NG 128      // graphs (B*G)
#define FH 128      // feature/hidden dim
#define APITCH 68   // A-chunk float pitch: 272 B row (16B-aligned), bank stride 4 -> 2-way (free)
#define XPITCH 136
#define BN_EPS 1e-5f

typedef __attribute__((ext_vector_type(8))) short s8v;            // 8 bf16 = 4 VGPRs
typedef __attribute__((ext_vector_type(4))) float f4v;            // MFMA C/D
typedef __attribute__((ext_vector_type(4))) unsigned short us4v;  // native ushort4
typedef __attribute__((ext_vector_type(4))) unsigned int u4v;

__device__ inline unsigned short f2bf(float x) {   // RNE fp32 -> bf16 bits
    unsigned u = __float_as_uint(x);
    unsigned r = (u + 0x7fffu + ((u >> 16) & 1u)) >> 16;
    return (unsigned short)r;
}
__device__ inline float bf2f(unsigned short h) { return __uint_as_float(((unsigned)h) << 16); }

// pack hi16(f1):hi16(f0) -> one u32 (exact bf16 for integer-valued floats < 256)
__device__ inline unsigned bfpack(int f1bits, int f0bits) {
    return __builtin_amdgcn_perm((unsigned)f1bits, (unsigned)f0bits, 0x07060302u);
}

// ---------------- K1: degrees + norms + 32-bucket (dst128blk, src64chunk) packed edges;
//                 payload = (d&127)<<6 | (s&63); blocks >= NG pack W ----------------
__global__ __launch_bounds__(1024) void k_build(const int* __restrict__ edges,
                                                float* __restrict__ rs_out,
                                                float* __restrict__ rs_in,
                                                int* __restrict__ bofs,
                                                unsigned short* __restrict__ epk,
                                                const float* __restrict__ W0,
                                                const float* __restrict__ W1,
                                                unsigned short* __restrict__ WP) {
    int g = blockIdx.x;
    int tid = threadIdx.x;

    if (g >= NG) {
        int which = g - NG;
        const float* W = which ? W1 : W0;
        for (int task = tid; task < 2048; task += 1024) {
            int t = task >> 6;            // 0..31  (nt*4+kk)
            int lane = task & 63;
            int nt = t >> 2, kk = t & 3;
            int n = nt * 16 + (lane & 15);
            int k0 = kk * 32 + (lane >> 4) * 8;
            unsigned short* dh = WP + ((size_t)which * 2 + 0) * 16384 + ((size_t)t * 64 + lane) * 8;
            unsigned short* dl = WP + ((size_t)which * 2 + 1) * 16384 + ((size_t)t * 64 + lane) * 8;
#pragma unroll
            for (int j = 0; j < 8; j++) {
                float v = W[(size_t)(k0 + j) * FH + n];
                unsigned short h = f2bf(v);
                dh[j] = h;
                dl[j] = f2bf(v - bf2f(h));
            }
        }
        return;
    }

    const int* src = edges + (size_t)g * 2 * NE;
    const int* dst = src + NE;

    __shared__ int degO[NN], degI[NN];
    __shared__ int scanA[1024], scanB[1024];   // [bucket 32][replica 32] counts / scan ping-pong
    __shared__ int fill[1024];
    __shared__ unsigned short pk[NE];          // 16 KB packed edges

    for (int i = tid; i < NN; i += 1024) { degO[i] = 0; degI[i] = 0; }
    scanA[tid] = 0;
    __syncthreads();

    int rep = tid & 31;
    for (int u = tid; u < NE / 4; u += 1024) {
        int4 s = ((const int4*)src)[u];
        int4 d = ((const int4*)dst)[u];
        atomicAdd(&degO[s.x], 1); atomicAdd(&degO[s.y], 1);
        atomicAdd(&degO[s.z], 1); atomicAdd(&degO[s.w], 1);
        atomicAdd(&degI[d.x], 1); atomicAdd(&degI[d.y], 1);
        atomicAdd(&degI[d.z], 1); atomicAdd(&degI[d.w], 1);
        atomicAdd(&scanA[((((d.x >> 7) << 3) | (s.x >> 6)) << 5) + rep], 1);
        atomicAdd(&scanA[((((d.y >> 7) << 3) | (s.y >> 6)) << 5) + rep], 1);
        atomicAdd(&scanA[((((d.z >> 7) << 3) | (s.z >> 6)) << 5) + rep], 1);
        atomicAdd(&scanA[((((d.w >> 7) << 3) | (s.w >> 6)) << 5) + rep], 1);
    }
    __syncthreads();

    for (int i = tid; i < NN; i += 1024) {
        rs_out[g * NN + i] = rsqrtf((float)max(degO[i], 1));
        rs_in [g * NN + i] = rsqrtf((float)max(degI[i], 1));
    }

    // inclusive Hillis-Steele scan over the 1024 (bucket,replica) cells
    int* sA = scanA; int* sB = scanB;
    for (int off = 1; off < 1024; off <<= 1) {
        int v = sA[tid];
        if (tid >= off) v += sA[tid - off];
        sB[tid] = v;
        __syncthreads();
        int* t = sA; sA = sB; sB = t;
    }
    int excl = tid ? sA[tid - 1] : 0;
    fill[tid] = excl;
    if ((tid & 31) == 0) bofs[g * 33 + (tid >> 5)] = excl;   // bucket start = excl at cell b*32
    if (tid == 0) bofs[g * 33 + 32] = NE;
    __syncthreads();

    for (int u = tid; u < NE / 4; u += 1024) {
        int4 s = ((const int4*)src)[u];
        int4 d = ((const int4*)dst)[u];
        int c, p;
        c = ((((d.x >> 7) << 3) | (s.x >> 6)) << 5) + rep;
        p = atomicAdd(&fill[c], 1); pk[p] = (unsigned short)(((d.x & 127) << 6) | (s.x & 63));
        c = ((((d.y >> 7) << 3) | (s.y >> 6)) << 5) + rep;
        p = atomicAdd(&fill[c], 1); pk[p] = (unsigned short)(((d.y & 127) << 6) | (s.y & 63));
        c = ((((d.z >> 7) << 3) | (s.z >> 6)) << 5) + rep;
        p = atomicAdd(&fill[c], 1); pk[p] = (unsigned short)(((d.z & 127) << 6) | (s.z & 63));
        c = ((((d.w >> 7) << 3) | (s.w >> 6)) << 5) + rep;
        p = atomicAdd(&fill[c], 1); pk[p] = (unsigned short)(((d.w & 127) << 6) | (s.w & 63));
    }
    __syncthreads();
    // 8192 ushorts = 1024 int4, exactly one per thread
    ((int4*)(epk + (size_t)g * NE))[tid] = ((const int4*)pk)[tid];
}

// ---------------- K2: Y1f = pack_Bfrag((feats @ W0) * rs)  (hi/lo split, 3 MFMA) ----------------
__global__ __launch_bounds__(256) void k_gemm_f32(const float* __restrict__ X,
                                                  const unsigned short* __restrict__ WPh,
                                                  const unsigned short* __restrict__ WPl,
                                                  const float* __restrict__ rs,
                                                  unsigned short* __restrict__ Yf) {
    __shared__ unsigned short xh[64 * XPITCH];   // 17 KB
    __shared__ unsigned short xl[64 * XPITCH];   // 17 KB
    int tid = threadIdx.x;
    int sb = blockIdx.y;
    size_t r0 = (size_t)blockIdx.x * NN + (size_t)sb * 64;

    const float4* Xv = (const float4*)(X + r0 * FH);
#pragma unroll
    for (int i = 0; i < 8; i++) {
        int u = tid + i * 256;                 // 2048 float4 = 64x128
        int row = u >> 5, c4 = (u & 31) * 4;
        float4 v = Xv[u];
        int off = row * XPITCH + c4;
        unsigned short h0 = f2bf(v.x), h1 = f2bf(v.y), h2 = f2bf(v.z), h3 = f2bf(v.w);
        us4v hv, lv;
        hv.x = h0; hv.y = h1; hv.z = h2; hv.w = h3;
        lv.x = f2bf(v.x - bf2f(h0));
        lv.y = f2bf(v.y - bf2f(h1));
        lv.z = f2bf(v.z - bf2f(h2));
        lv.w = f2bf(v.w - bf2f(h3));
        *(us4v*)(xh + off) = hv;
        *(us4v*)(xl + off) = lv;
    }
    __syncthreads();

    int lane = tid & 63, w = tid >> 6;
    int quad = lane >> 4, m = lane & 15;
    int arow = w * 16 + m;

    f4v acc[8];
#pragma unroll
    for (int nt = 0; nt < 8; nt++) acc[nt] = (f4v){0.f, 0.f, 0.f, 0.f};

#pragma unroll
    for (int kk = 0; kk < 4; kk++) {
        s8v ah = *(const s8v*)&xh[arow * XPITCH + kk * 32 + quad * 8];
        s8v al = *(const s8v*)&xl[arow * XPITCH + kk * 32 + quad * 8];
#pragma unroll
        for (int nt = 0; nt < 8; nt++) {
            s8v bh = *(const s8v*)(WPh + ((size_t)(nt * 4 + kk) * 64 + lane) * 8);
            s8v bl = *(const s8v*)(WPl + ((size_t)(nt * 4 + kk) * 64 + lane) * 8);
            acc[nt] = __builtin_amdgcn_mfma_f32_16x16x32_bf16(ah, bh, acc[nt], 0, 0, 0);
            acc[nt] = __builtin_amdgcn_mfma_f32_16x16x32_bf16(al, bh, acc[nt], 0, 0, 0);
            acc[nt] = __builtin_amdgcn_mfma_f32_16x16x32_bf16(ah, bl, acc[nt], 0, 0, 0);
        }
    }

    int orow = w * 16 + quad * 4;
    float4 rsv = *(const float4*)(rs + r0 + orow);
    int tag = (w * 2 + (quad >> 1)) & 3;
    int kko = sb * 2 + (w >> 1);
    int j0  = (quad & 1) * 4;
    unsigned short* of = Yf + (size_t)blockIdx.x * (NN * FH);
#pragma unroll
    for (int nt = 0; nt < 8; nt++) {
        us4v v;
        v.x = f2bf(acc[nt][0] * rsv.x);
        v.y = f2bf(acc[nt][1] * rsv.y);
        v.z = f2bf(acc[nt][2] * rsv.z);
        v.w = f2bf(acc[nt][3] * rsv.w);
        *(us4v*)(of + (((size_t)kko * 8 + nt) * 64 + (m + 16 * tag)) * 8 + j0) = v;
    }
}

// ---------------- K3: FUSED dense-A MFMA aggregation (128-row dst tile, pipelined) + gemm2 -> Y2f ----------------
// 512 blocks x 1024 thr (16 waves = 8 Mtiles x 2 Nhalves): B-chunk staged once per 128 output
// rows (halves Y1 re-reads vs 64-row tiles), per-CU barrier count halves, 2 blocks/CU (full occupancy).
__global__ __launch_bounds__(1024) void k_fused(const unsigned short* __restrict__ Y1f,
                                                const int* __restrict__ bofs,
                                                const unsigned short* __restrict__ epk,
                                                const float* __restrict__ rs_in,
                                                const float* __restrict__ rs_out,
                                                const float* __restrict__ bias,
                                                const unsigned short* __restrict__ WPh,
                                                const unsigned short* __restrict__ WPl,
                                                unsigned short* __restrict__ Y2f) {
    int g  = blockIdx.x;
    int sb = blockIdx.y;   // 0..3
    int tid = threadIdx.x;
    int lane = tid & 63, w16 = tid >> 6;   // 16 waves
    int quad = lane >> 4, m = lane & 15;
    int mt = w16 & 7, nh = w16 >> 3;
    int base = sb * 128;

    __shared__ float Af[128 * APITCH];            // 34816 B; hs aliases this after agg
    __shared__ unsigned short Bs[2 * 8 * 64 * 8]; // 16384 B B-chunk
    unsigned short* hs = (unsigned short*)Af;     // 128*XPITCH*2 = 34816 B exactly
    __shared__ float rsin_s[128];
    __shared__ int bo_s[9];

    const unsigned short* ep = epk + (size_t)g * NE;
    const int4* Yi4 = (const int4*)(Y1f + (size_t)g * (NN * FH));
    int4* Bi4 = (int4*)Bs;

    // prologue: B[0] load issued immediately (1 int4/thread)
    int4 rB0 = Yi4[tid];

    if (tid < 128) rsin_s[tid] = rs_in[g * NN + base + tid];
    if (tid < 9) bo_s[tid] = bofs[g * 33 + sb * 8 + tid];
    __syncthreads();
    int evNext = -1;
    { int e0 = bo_s[0] + tid; if (e0 < bo_s[1]) evNext = (int)ep[e0]; }

    f4v acc[4];
#pragma unroll
    for (int j = 0; j < 4; j++) acc[j] = (f4v){0.f, 0.f, 0.f, 0.f};

    for (int p = 0; p < 8; p++) {
        if (p) __syncthreads();             // prior pass's Af/Bs reads done
        float4 z4 = {0.f, 0.f, 0.f, 0.f};
        for (int i = tid; i < 128 * APITCH / 4; i += 1024) ((float4*)Af)[i] = z4;
        Bi4[tid] = rB0;                     // commit pass-p B-chunk
        __syncthreads();                    // zero + B visible
        if (evNext >= 0) atomicAdd(&Af[(evNext >> 6) * APITCH + (evNext & 63)], 1.0f);
        for (int e = bo_s[p] + tid + 1024; e < bo_s[p + 1]; e += 1024) {  // practically never taken
            int v = ep[e];
            atomicAdd(&Af[(v >> 6) * APITCH + (v & 63)], 1.0f);
        }
        __syncthreads();                    // A ready
        if (p < 7) {                        // prefetch pass p+1 (flies under MFMA)
            rB0 = Yi4[(p + 1) * 1024 + tid];
            int e1 = bo_s[p + 1] + tid;
            evNext = (e1 < bo_s[p + 2]) ? (int)ep[e1] : -1;
        }
#pragma unroll
        for (int kkl = 0; kkl < 2; kkl++) {
            s8v bf[4];
#pragma unroll
            for (int j = 0; j < 4; j++)
                bf[j] = *(const s8v*)&Bs[((kkl * 8 + nh * 4 + j) * 64 + lane) * 8];
            const int4* ap = (const int4*)&Af[(mt * 16 + m) * APITCH + kkl * 32 + quad * 8];
            int4 a0 = ap[0];
            int4 a1 = ap[1];
            union { u4v u; s8v s; } cv;
            cv.u.x = bfpack(a0.y, a0.x);
            cv.u.y = bfpack(a0.w, a0.z);
            cv.u.z = bfpack(a1.y, a1.x);
            cv.u.w = bfpack(a1.w, a1.z);
            s8v af = cv.s;
#pragma unroll
            for (int j = 0; j < 4; j++)
                acc[j] = __builtin_amdgcn_mfma_f32_16x16x32_bf16(af, bf[j], acc[j], 0, 0, 0);
        }
    }
    __syncthreads();   // agg done; Af reusable as hs

    // ---- conv1 epilogue: h = relu(rs_in*agg + b0) -> hs (natural [row][feat]) ----
#pragma unroll
    for (int j = 0; j < 4; j++) {
        int feat = (nh * 4 + j) * 16 + m;
        float bv = bias[feat];
#pragma unroll
        for (int i = 0; i < 4; i++) {
            int r = mt * 16 + quad * 4 + i;
            float hv = fmaxf(fmaf(rsin_s[r], acc[j][i], bv), 0.f);
            hs[r * XPITCH + feat] = f2bf(hv);
        }
    }
    __syncthreads();

    // ---- gemm2: Y2 = (h @ W1) * rs_out, packed B-fragment output ----
    f4v acc2[4];
#pragma unroll
    for (int j = 0; j < 4; j++) acc2[j] = (f4v){0.f, 0.f, 0.f, 0.f};

#pragma unroll
    for (int kk = 0; kk < 4; kk++) {
        s8v ah = *(const s8v*)&hs[(mt * 16 + m) * XPITCH + kk * 32 + quad * 8];
#pragma unroll
        for (int j = 0; j < 4; j++) {
            int nt = nh * 4 + j;
            s8v bh = *(const s8v*)(WPh + ((size_t)(nt * 4 + kk) * 64 + lane) * 8);
            s8v bl = *(const s8v*)(WPl + ((size_t)(nt * 4 + kk) * 64 + lane) * 8);
            acc2[j] = __builtin_amdgcn_mfma_f32_16x16x32_bf16(ah, bh, acc2[j], 0, 0, 0);
            acc2[j] = __builtin_amdgcn_mfma_f32_16x16x32_bf16(ah, bl, acc2[j], 0, 0, 0);
        }
    }

    int orow = mt * 16 + quad * 4;
    float4 rsv = *(const float4*)(rs_out + (size_t)g * NN + base + orow);
    int tag = (mt & 1) * 2 + (quad >> 1);
    int kko = sb * 4 + (mt >> 1);
    int j0  = (quad & 1) * 4;
    unsigned short* of = Y2f + (size_t)g * (NN * FH);
#pragma unroll
    for (int j = 0; j < 4; j++) {
        int nt = nh * 4 + j;
        us4v v;
        v.x = f2bf(acc2[j][0] * rsv.x);
        v.y = f2bf(acc2[j][1] * rsv.y);
        v.z = f2bf(acc2[j][2] * rsv.z);
        v.w = f2bf(acc2[j][3] * rsv.w);
        *(us4v*)(of + (((size_t)kko * 8 + nt) * 64 + (m + 16 * tag)) * 8 + j0) = v;
    }
}

// ---------------- K4: dense-A MFMA aggregation (128-row tile, pipelined) + relu + node-sum -> partial ----------------
__global__ __launch_bounds__(1024) void k_gather_mean(const unsigned short* __restrict__ Y2f,
                                                      const int* __restrict__ bofs,
                                                      const unsigned short* __restrict__ epk,
                                                      const float* __restrict__ rs_in,
                                                      const float* __restrict__ bias,
                                                      float* __restrict__ partial) {
    int g  = blockIdx.x;
    int sb = blockIdx.y;   // 0..3
    int tid = threadIdx.x;
    int lane = tid & 63, w16 = tid >> 6;
    int quad = lane >> 4, m = lane & 15;
    int mt = w16 & 7, nh = w16 >> 3;
    int base = sb * 128;

    __shared__ float Af[128 * APITCH];            // 34816 B; red aliases this after agg
    __shared__ unsigned short Bs[2 * 8 * 64 * 8]; // 16384 B
    float* red = (float*)Af;                      // [16][64][4] = 16384 B
    __shared__ float rsin_s[128];
    __shared__ int bo_s[9];

    const unsigned short* ep = epk + (size_t)g * NE;
    const int4* Yi4 = (const int4*)(Y2f + (size_t)g * (NN * FH));
    int4* Bi4 = (int4*)Bs;

    int4 rB0 = Yi4[tid];

    if (tid < 128) rsin_s[tid] = rs_in[g * NN + base + tid];
    if (tid < 9) bo_s[tid] = bofs[g * 33 + sb * 8 + tid];
    __syncthreads();
    int evNext = -1;
    { int e0 = bo_s[0] + tid; if (e0 < bo_s[1]) evNext = (int)ep[e0]; }

    f4v acc[4];
#pragma unroll
    for (int j = 0; j < 4; j++) acc[j] = (f4v){0.f, 0.f, 0.f, 0.f};

    for (int p = 0; p < 8; p++) {
        if (p) __syncthreads();
        float4 z4 = {0.f, 0.f, 0.f, 0.f};
        for (int i = tid; i < 128 * APITCH / 4; i += 1024) ((float4*)Af)[i] = z4;
        Bi4[tid] = rB0;
        __syncthreads();
        if (evNext >= 0) atomicAdd(&Af[(evNext >> 6) * APITCH + (evNext & 63)], 1.0f);
        for (int e = bo_s[p] + tid + 1024; e < bo_s[p + 1]; e += 1024) {
            int v = ep[e];
            atomicAdd(&Af[(v >> 6) * APITCH + (v & 63)], 1.0f);
        }
        __syncthreads();
        if (p < 7) {
            rB0 = Yi4[(p + 1) * 1024 + tid];
            int e1 = bo_s[p + 1] + tid;
            evNext = (e1 < bo_s[p + 2]) ? (int)ep[e1] : -1;
        }
#pragma unroll
        for (int kkl = 0; kkl < 2; kkl++) {
            s8v bf[4];
#pragma unroll
            for (int j = 0; j < 4; j++)
                bf[j] = *(const s8v*)&Bs[((kkl * 8 + nh * 4 + j) * 64 + lane) * 8];
            const int4* ap = (const int4*)&Af[(mt * 16 + m) * APITCH + kkl * 32 + quad * 8];
            int4 a0 = ap[0];
            int4 a1 = ap[1];
            union { u4v u; s8v s; } cv;
            cv.u.x = bfpack(a0.y, a0.x);
            cv.u.y = bfpack(a0.w, a0.z);
            cv.u.z = bfpack(a1.y, a1.x);
            cv.u.w = bfpack(a1.w, a1.z);
            s8v af = cv.s;
#pragma unroll
            for (int j = 0; j < 4; j++)
                acc[j] = __builtin_amdgcn_mfma_f32_16x16x32_bf16(af, bf[j], acc[j], 0, 0, 0);
        }
    }
    __syncthreads();   // agg done; Af reusable as red

    // ---- epilogue: relu(rs_in*agg + b1) summed over this lane's 4 rows, per nt ----
#pragma unroll
    for (int j = 0; j < 4; j++) {
        int feat = (nh * 4 + j) * 16 + m;
        float bv = bias[feat];
        float s = 0.f;
#pragma unroll
        for (int i = 0; i < 4; i++) {
            int r = mt * 16 + quad * 4 + i;
            s += fmaxf(fmaf(rsin_s[r], acc[j][i], bv), 0.f);
        }
        red[(w16 * 64 + lane) * 4 + j] = s;
    }
    __syncthreads();
    if (tid < FH) {
        int f = tid;
        int nt = f >> 4, mm = f & 15;
        int nhh = nt >> 2, jj = nt & 3;
        float t = 0.f;
#pragma unroll
        for (int mtt = 0; mtt < 8; mtt++)
#pragma unroll
            for (int q = 0; q < 4; q++)
                t += red[(((nhh * 8 + mtt) * 64) + q * 16 + mm) * 4 + jj];
        partial[((size_t)g * 4 + sb) * FH + f] = t;
    }
}

// ---------------- K5: z = (sum partials)/512 @ Wt + bt; BN eval; relu ----------------
__global__ __launch_bounds__(128) void k_head(const float* __restrict__ partial,
                                              const float* __restrict__ Wt,
                                              const float* __restrict__ bt,
                                              const float* __restrict__ gamma,
                                              const float* __restrict__ beta,
                                              const float* __restrict__ rmean,
                                              const float* __restrict__ rvar,
                                              float* __restrict__ out) {
    int g = blockIdx.x;
    int j = threadIdx.x;
    __shared__ float e[FH];
    float acc4 = 0.f;
#pragma unroll
    for (int q = 0; q < 4; q++) acc4 += partial[((size_t)g * 4 + q) * FH + j];
    e[j] = acc4 * (1.0f / (float)NN);
    __syncthreads();
    float acc = bt[j];
#pragma unroll 8
    for (int k = 0; k < FH; k++) acc += e[k] * Wt[(size_t)k * FH + j];
    float z = gamma[j] * (acc - rmean[j]) * rsqrtf(rvar[j] + BN_EPS) + beta[j];
    out[g * FH + j] = fmaxf(z, 0.f);
}

extern "C" void kernel_launch(void* const* d_in, const int* in_sizes, int n_in,
                              void* d_out, int out_size, void* d_ws, size_t ws_size,
                              hipStream_t stream) {
    const float* feats = (const float*)d_in[0];
    const int*   edges = (const int*)d_in[1];
    const float* W0    = (const float*)d_in[2];
    const float* b0    = (const float*)d_in[3];
    const float* W1    = (const float*)d_in[4];
    const float* b1    = (const float*)d_in[5];
    const float* Wt    = (const float*)d_in[6];
    const float* bt    = (const float*)d_in[7];
    const float* gamma = (const float*)d_in[8];
    const float* beta  = (const float*)d_in[9];
    const float* rmean = (const float*)d_in[10];
    const float* rvar  = (const float*)d_in[11];
    float* out = (float*)d_out;

    // workspace layout
    char* w = (char*)d_ws;
    float* rs_out  = (float*)w;   w += sizeof(float) * NG * NN;
    float* rs_in   = (float*)w;   w += sizeof(float) * NG * NN;
    int*   bofs    = (int*)w;     w += sizeof(int) * NG * 33;              // 16896 B (16B multiple)
    unsigned short* epk = (unsigned short*)w; w += sizeof(unsigned short) * (size_t)NG * NE; // 2 MB
    unsigned short* WP  = (unsigned short*)w; w += sizeof(unsigned short) * 4 * 16384;       // 128 KB
    unsigned short* Y1  = (unsigned short*)w; w += sizeof(unsigned short) * (size_t)NG * NN * FH; // 16 MB
    unsigned short* Y2  = (unsigned short*)w; w += sizeof(unsigned short) * (size_t)NG * NN * FH; // 16 MB
    float* partial = (float*)w;   w += sizeof(float) * NG * 4 * FH;

    unsigned short* WPh0 = WP;
    unsigned short* WPl0 = WP + 16384;
    unsigned short* WPh1 = WP + 32768;
    unsigned short* WPl1 = WP + 49152;

    // K1: norms + bucketed packed edges; 2 extra blocks pack W0/W1
    k_build<<<NG + 2, 1024, 0, stream>>>(edges, rs_out, rs_in, bofs, epk, W0, W1, WP);

    // K2: conv1 gemm (feats -> Y1, B-fragment packed)
    k_gemm_f32<<<dim3(NG, 8), 256, 0, stream>>>(feats, WPh0, WPl0, rs_out, Y1);

    // K3: fused dense-A MFMA aggregation (128-row tiles) + conv2 gemm (Y1 -> Y2, packed)
    k_fused<<<dim3(NG, 4), 1024, 0, stream>>>(Y1, bofs, epk, rs_in, rs_out, b0, WPh1, WPl1, Y2);

    // K4: dense-A MFMA aggregation (128-row tiles, conv2) + node-mean -> partial
    k_gather_mean<<<dim3(NG, 4), 1024, 0, stream>>>(Y2, bofs, epk, rs_in, b1, partial);

    // K5: head
    k_head<<<NG, 128, 0, stream>>>(partial, Wt, bt, gamma, beta, rmean, rvar, out);

    (void)in_sizes; (void)n_in; (void)out_size; (void)ws_size;
}